// Round 17
// baseline (102.708 us; speedup 1.0000x reference)
//
#include <hip/hip_runtime.h>

// B=8,H=8,S=1024,D=64 fp32 attention, raw-exp softmax, multiplicative key mask.
// Outputs: context[64,1024,64] then scores[64,1024,1024], both fp32.
// R17: two-pass overlap. Pass1 rowsum->inv (ws). Pass2: compute with inv known,
// stage NORMALIZED E-f16 in per-wave private LDS chunks (dbuf, no barriers),
// flush chunk c-1 as 2 nt stores/kt (4 rows x 256 B segments = full lines),
// issued AFTER each kt's prefetch loads. Tests the untested matrix cell:
// in-loop + good-shape + nt. PV uses normalized pf -> no-inv epilogue.

typedef float    f32x4 __attribute__((ext_vector_type(4)));
typedef _Float16 f16x8 __attribute__((ext_vector_type(8)));
typedef _Float16 f16x4 __attribute__((ext_vector_type(4)));

#define MFMA32(A, B, C) __builtin_amdgcn_mfma_f32_16x16x32_f16((A), (B), (C), 0, 0, 0)
#define MFMA16(A, B, C) __builtin_amdgcn_mfma_f32_16x16x16f16((A), (B), (C), 0, 0, 0)

#define BHN 64
#define SEQ 1024
#define DIM 64

__device__ inline f16x8 cvt8(f32x4 a, f32x4 b) {
    f16x8 r;
    r[0] = (_Float16)a[0]; r[1] = (_Float16)a[1]; r[2] = (_Float16)a[2]; r[3] = (_Float16)a[3];
    r[4] = (_Float16)b[0]; r[5] = (_Float16)b[1]; r[6] = (_Float16)b[2]; r[7] = (_Float16)b[3];
    return r;
}

// Pre-pass: K -> f16 same layout; V -> f16 repacked for PV (VTP, as R9/R16).
__global__ __launch_bounds__(256)
void cvt_kv(const float* __restrict__ K, const float* __restrict__ V,
            _Float16* __restrict__ Kh, _Float16* __restrict__ VTP)
{
    __shared__ _Float16 tile[128 * 65];
    const int bh = blockIdx.x >> 3;
    const int kc = blockIdx.x & 7;
    const int t  = threadIdx.x;
    const size_t base = ((size_t)bh * SEQ + (size_t)kc * 128) * DIM;

    for (int it = 0; it < 8; ++it) {
        int idx = it * 256 + t;
        int key = idx >> 4;
        int c4  = idx & 15;
        f32x4 kv = *(const f32x4*)(K + base + key * DIM + c4 * 4);
        f32x4 vv = *(const f32x4*)(V + base + key * DIM + c4 * 4);
        f16x4 kh4;
        kh4[0] = (_Float16)kv[0]; kh4[1] = (_Float16)kv[1];
        kh4[2] = (_Float16)kv[2]; kh4[3] = (_Float16)kv[3];
        *(f16x4*)(Kh + base + key * DIM + c4 * 4) = kh4;
        tile[key * 65 + c4 * 4 + 0] = (_Float16)vv[0];
        tile[key * 65 + c4 * 4 + 1] = (_Float16)vv[1];
        tile[key * 65 + c4 * 4 + 2] = (_Float16)vv[2];
        tile[key * 65 + c4 * 4 + 3] = (_Float16)vv[3];
    }
    __syncthreads();
    for (int it = 0; it < 8; ++it) {
        int flat = it * 256 + t;
        int ktl  = flat >> 8;
        int rem  = flat & 255;
        int l    = rem >> 2;
        int c    = rem & 3;
        f16x4 o;
        #pragma unroll
        for (int j = 0; j < 4; ++j)
            o[j] = tile[(ktl * 16 + ((l >> 4) << 2) + j) * 65 + c * 16 + (l & 15)];
        *(f16x4*)(VTP + (((size_t)bh * 64 + kc * 8 + ktl) * 64 + l) * 16 + c * 4) = o;
    }
}

// Pass 1: rowsums -> inv. Grid 1024 (64 bh x 16 q-blocks of 64 rows), 4 waves =
// key quarters. Swapped QK^T (proven in R7).
template <bool PRECONV>
__global__ __launch_bounds__(256, 4)
void rowsum_k(const float* __restrict__ Q, const float* __restrict__ K,
              const float* __restrict__ mask, const _Float16* __restrict__ Kh,
              float* __restrict__ invp)
{
    __shared__ float rs[4][4][16];
    const int bid = blockIdx.x;
    const int wg  = ((bid & 7) << 7) | (bid >> 3);   // XCD-bijective (1024 % 8 == 0)
    const int bh  = wg >> 4;
    const int qb  = wg & 15;
    const int b   = bh >> 3;
    const int w    = threadIdx.x >> 6;
    const int lane = threadIdx.x & 63;
    const int col  = lane & 15;
    const int g    = lane >> 4;
    const int q0   = qb * 64;
    const int kb   = w * 256;
    const float scale = 0.125f;

    f16x8 qf[4][2];
    {
        const float* qbase = Q + ((size_t)bh * SEQ + q0) * DIM;
        #pragma unroll
        for (int s = 0; s < 4; ++s)
            #pragma unroll
            for (int f = 0; f < 2; ++f) {
                const float* p = qbase + (s * 16 + col) * DIM + f * 32 + g * 8;
                qf[s][f] = cvt8(*(const f32x4*)p, *(const f32x4*)(p + 4));
            }
    }
    const float* mb = mask + (size_t)b * SEQ + kb;

    float rsum[4] = {0.f, 0.f, 0.f, 0.f};
    #pragma unroll 1
    for (int kt = 0; kt < 16; ++kt) {
        f16x8 kf0, kf1;
        if (PRECONV) {
            const _Float16* kp = Kh + ((size_t)bh * SEQ + kb + kt * 16 + col) * DIM + g * 8;
            kf0 = *(const f16x8*)kp;
            kf1 = *(const f16x8*)(kp + 32);
        } else {
            const float* kp = K + ((size_t)bh * SEQ + kb + kt * 16 + col) * DIM + g * 8;
            kf0 = cvt8(*(const f32x4*)kp,        *(const f32x4*)(kp + 4));
            kf1 = cvt8(*(const f32x4*)(kp + 32), *(const f32x4*)(kp + 36));
        }
        f32x4 m4 = *(const f32x4*)(mb + kt * 16 + g * 4);
        #pragma unroll
        for (int s = 0; s < 4; ++s) {
            f32x4 acc = {0.f, 0.f, 0.f, 0.f};
            acc = MFMA32(kf0, qf[s][0], acc);
            acc = MFMA32(kf1, qf[s][1], acc);
            rsum[s] += __expf(acc[0] * scale) * m4[0] + __expf(acc[1] * scale) * m4[1]
                     + __expf(acc[2] * scale) * m4[2] + __expf(acc[3] * scale) * m4[3];
        }
    }
    #pragma unroll
    for (int s = 0; s < 4; ++s) {
        float r = rsum[s];
        r += __shfl_xor(r, 16, 64);
        r += __shfl_xor(r, 32, 64);
        rsum[s] = r;
    }
    if (g == 0) {
        #pragma unroll
        for (int s = 0; s < 4; ++s) rs[w][s][col] = rsum[s];
    }
    __syncthreads();
    if (w == 0) {
        const int r = lane;   // 64 rows
        const float t = rs[0][r >> 4][r & 15] + rs[1][r >> 4][r & 15]
                      + rs[2][r >> 4][r & 15] + rs[3][r >> 4][r & 15];
        invp[(size_t)bh * SEQ + q0 + r] = 1.0f / (t + 1e-8f);
    }
}

// Pass 2: scores (in-loop chunk-staged nt flush) + PV. Grid 2048 (64 bh x 32
// q-blocks of 32 rows), 4 waves = key quarters. Per-wave-private LDS chunks:
// [2 bufs][32 rows][64 keys] f16 = 8 KB/wave. No barriers in the main loop.
template <bool PRECONV>
__global__ __launch_bounds__(256, 2)
void scorepv_k(const float* __restrict__ Q, const float* __restrict__ K,
               const float* __restrict__ V, const float* __restrict__ mask,
               const _Float16* __restrict__ Kh, const _Float16* __restrict__ VTP,
               const float* __restrict__ invp,
               float* __restrict__ ctx, float* __restrict__ scores)
{
    __shared__ _Float16 EC[4 * 2 * 32 * 64];   // 32 KB; aliased as cbuf later

    const int bid = blockIdx.x;
    const int wg  = ((bid & 7) << 8) | (bid >> 3);   // XCD-bijective (2048 % 8 == 0)
    const int bh  = wg >> 5;
    const int qb  = wg & 31;
    const int b   = bh >> 3;
    const int w    = threadIdx.x >> 6;
    const int lane = threadIdx.x & 63;
    const int col  = lane & 15;
    const int g    = lane >> 4;
    const int q0   = qb * 32;
    const int kb   = w * 256;
    const float scale = 0.125f;
    char* ECw = (char*)EC + w * 8192;   // this wave's 2 chunk buffers

    // ---- Q fragments + inv (known upfront)
    f16x8 qf[2][2];
    {
        const float* qbase = Q + ((size_t)bh * SEQ + q0) * DIM;
        #pragma unroll
        for (int s = 0; s < 2; ++s)
            #pragma unroll
            for (int f = 0; f < 2; ++f) {
                const float* p = qbase + (s * 16 + col) * DIM + f * 32 + g * 8;
                qf[s][f] = cvt8(*(const f32x4*)p, *(const f32x4*)(p + 4));
            }
    }
    float inv[2];
    inv[0] = invp[(size_t)bh * SEQ + q0 + col];
    inv[1] = invp[(size_t)bh * SEQ + q0 + 16 + col];

    const float* mb = mask + (size_t)b * SEQ + kb;
    const _Float16* kbase = Kh + ((size_t)bh * SEQ + kb + col) * DIM + g * 8;
    const _Float16* vtpb  = VTP + (((size_t)bh * 64 + w * 16) * 64 + lane) * 16;
    float* srow = scores + ((size_t)bh * SEQ + q0) * SEQ + kb;

    f32x4 cacc[2][4];
    #pragma unroll
    for (int s = 0; s < 2; ++s)
        #pragma unroll
        for (int dt = 0; dt < 4; ++dt) cacc[s][dt] = (f32x4){0.f, 0.f, 0.f, 0.f};

    auto loadS = [&](int kt, f16x8& a, f16x8& c, f16x8& x, f16x8& y, f32x4& m) {
        if (PRECONV) {
            a = *(const f16x8*)(kbase + (size_t)kt * 16 * DIM);
            c = *(const f16x8*)(kbase + (size_t)kt * 16 * DIM + 32);
            x = *(const f16x8*)(vtpb + (size_t)kt * 64 * 16);
            y = *(const f16x8*)(vtpb + (size_t)kt * 64 * 16 + 8);
        } else {
            const float* kp = K + ((size_t)bh * SEQ + kb + kt * 16 + col) * DIM + g * 8;
            a = cvt8(*(const f32x4*)kp,        *(const f32x4*)(kp + 4));
            c = cvt8(*(const f32x4*)(kp + 32), *(const f32x4*)(kp + 36));
            #pragma unroll
            for (int e = 0; e < 8; ++e) {
                x[e] = (_Float16)V[((size_t)bh * SEQ + kb + kt * 16 + g * 4 + (e & 3)) * DIM + (e >> 2) * 16 + col];
                y[e] = (_Float16)V[((size_t)bh * SEQ + kb + kt * 16 + g * 4 + (e & 3)) * DIM + (2 + (e >> 2)) * 16 + col];
            }
        }
        m = *(const f32x4*)(mb + kt * 16 + g * 4);
    };

    // flush one store-instr m (0..7) of chunk cf from buf fb: 4 rows x 256 B nt.
    auto flushInstr = [&](int cf, int fb, int m) {
        const int rm  = m * 4 + g;                       // row 0..31
        const int gsw = (col ^ (rm & 15));               // conflict-free granule
        f16x4 ev = *(const f16x4*)(ECw + fb * 4096 + rm * 128 + gsw * 8);
        f32x4 o;
        o[0] = (float)ev[0]; o[1] = (float)ev[1];
        o[2] = (float)ev[2]; o[3] = (float)ev[3];
        __builtin_nontemporal_store(o, (f32x4*)(srow + (size_t)rm * SEQ + cf * 64 + col * 4));
    };

    // ---- main loop: 16 kt, 4 chunks of 4 kt; flush chunk c-1 during chunk c.
    f16x8 k0, k1, va, vb;
    f32x4 m4;
    loadS(0, k0, k1, va, vb, m4);

    #pragma unroll 1
    for (int kt = 0; kt < 16; ++kt) {
        // 1) issue next loads FIRST (so no load ever waits behind our stores)
        f16x8 n0, n1, nx, ny;
        f32x4 nm;
        loadS((kt + 1) & 15, n0, n1, nx, ny, nm);

        // 2) flush 2 store-instrs of the previous chunk
        if (kt >= 4) {
            const int cf = (kt >> 2) - 1;
            const int fb = cf & 1;
            flushInstr(cf, fb, (kt & 3) * 2);
            flushInstr(cf, fb, (kt & 3) * 2 + 1);
        }

        // 3) body: QK MFMA, exp, normalize, stage to LDS, PV
        const int buf = (kt >> 2) & 1;
        f16x4 pf[2];
        #pragma unroll
        for (int s = 0; s < 2; ++s) {
            f32x4 acc = {0.f, 0.f, 0.f, 0.f};
            acc = MFMA32(k0, qf[s][0], acc);
            acc = MFMA32(k1, qf[s][1], acc);
            const float p0 = __expf(acc[0] * scale) * m4[0] * inv[s];
            const float p1 = __expf(acc[1] * scale) * m4[1] * inv[s];
            const float p2 = __expf(acc[2] * scale) * m4[2] * inv[s];
            const float p3 = __expf(acc[3] * scale) * m4[3] * inv[s];
            f16x4 eh;
            eh[0] = (_Float16)p0; eh[1] = (_Float16)p1;
            eh[2] = (_Float16)p2; eh[3] = (_Float16)p3;
            pf[s] = eh;
            const int row = s * 16 + col;
            const int gg  = ((kt & 3) * 4 + g) ^ (row & 15);
            *(f16x4*)(ECw + buf * 4096 + row * 128 + gg * 8) = eh;
        }
        {
            f16x4 vt0 = __builtin_shufflevector(va, va, 0, 1, 2, 3);
            f16x4 vt1 = __builtin_shufflevector(va, va, 4, 5, 6, 7);
            f16x4 vt2 = __builtin_shufflevector(vb, vb, 0, 1, 2, 3);
            f16x4 vt3 = __builtin_shufflevector(vb, vb, 4, 5, 6, 7);
            cacc[0][0] = MFMA16(vt0, pf[0], cacc[0][0]);
            cacc[1][0] = MFMA16(vt0, pf[1], cacc[1][0]);
            cacc[0][1] = MFMA16(vt1, pf[0], cacc[0][1]);
            cacc[1][1] = MFMA16(vt1, pf[1], cacc[1][1]);
            cacc[0][2] = MFMA16(vt2, pf[0], cacc[0][2]);
            cacc[1][2] = MFMA16(vt2, pf[1], cacc[1][2]);
            cacc[0][3] = MFMA16(vt3, pf[0], cacc[0][3]);
            cacc[1][3] = MFMA16(vt3, pf[1], cacc[1][3]);
        }
        k0 = n0; k1 = n1; va = nx; vb = ny; m4 = nm;
    }

    // ---- tail: flush chunk 3 (buf 1)
    #pragma unroll
    for (int m = 0; m < 8; ++m) flushInstr(3, 1, m);

    __syncthreads();

    // ---- PV combine (cacc already normalized): alias EC as float scratch.
    float* dumpf = (float*)EC;
    if (w != 0) {
        float* d = dumpf + (w - 1) * 2048;
        #pragma unroll
        for (int s = 0; s < 2; ++s)
            #pragma unroll
            for (int dt = 0; dt < 4; ++dt)
                #pragma unroll
                for (int i = 0; i < 4; ++i)
                    d[((s * 4 + dt) * 4 + i) * 64 + lane] = cacc[s][dt][i];
    }
    __syncthreads();
    if (w == 0) {
        #pragma unroll
        for (int s = 0; s < 2; ++s)
            #pragma unroll
            for (int dt = 0; dt < 4; ++dt) {
                f32x4 r = cacc[s][dt];
                #pragma unroll
                for (int ww = 0; ww < 3; ++ww) {
                    const float* d = dumpf + ww * 2048;
                    #pragma unroll
                    for (int i = 0; i < 4; ++i)
                        r[i] += d[((s * 4 + dt) * 4 + i) * 64 + lane];
                }
                *(f32x4*)(ctx + ((size_t)bh * SEQ + q0 + s * 16 + col) * DIM + dt * 16 + g * 4) = r;
            }
    }
}

extern "C" void kernel_launch(void* const* d_in, const int* in_sizes, int n_in,
                              void* d_out, int out_size, void* d_ws, size_t ws_size,
                              hipStream_t stream)
{
    const float* Q    = (const float*)d_in[0];
    const float* K    = (const float*)d_in[1];
    const float* V    = (const float*)d_in[2];
    const float* mask = (const float*)d_in[3];
    float* ctx    = (float*)d_out;
    float* scores = ctx + (size_t)BHN * SEQ * DIM;

    const size_t elems = (size_t)BHN * SEQ * DIM;                 // 4,194,304
    const size_t inv_bytes = (size_t)BHN * SEQ * sizeof(float);   // 256 KB
    const size_t need = elems * 2 * sizeof(_Float16) + inv_bytes; // ~16.25 MB

    if (ws_size >= need) {
        _Float16* Kh   = (_Float16*)d_ws;
        _Float16* VTP  = Kh + elems;
        float*    invp = (float*)(VTP + elems);
        cvt_kv<<<512, 256, 0, stream>>>(K, V, Kh, VTP);
        rowsum_k<true><<<1024, 256, 0, stream>>>(Q, K, mask, Kh, invp);
        scorepv_k<true><<<2048, 256, 0, stream>>>(Q, K, V, mask, Kh, VTP, invp, ctx, scores);
    } else {
        float* invp = (float*)d_ws;   // needs only 256 KB
        rowsum_k<false><<<1024, 256, 0, stream>>>(Q, K, mask, nullptr, invp);
        scorepv_k<false><<<2048, 256, 0, stream>>>(Q, K, V, mask, nullptr, nullptr, invp, ctx, scores);
    }
}